// Round 8
// baseline (415.964 us; speedup 1.0000x reference)
//
#include <hip/hip_runtime.h>
#include <hip/hip_bf16.h>

typedef unsigned short u16;
typedef unsigned int u32;
typedef __attribute__((ext_vector_type(8))) __bf16 bf16x8;
typedef __attribute__((ext_vector_type(4))) float f32x4;
typedef __attribute__((ext_vector_type(16))) float f32x16;

#define N_TOK 4096
#define DIMF  514
#define KPAD  544      // 17*32, zero-padded K for QKV gemm
#define OUT3  768
#define OUTD  256
#define RDIM  512
#define DIMP  640      // 5*128, zero-padded Wo output-dim for proj staging
#define FDIM  1542
#define SHIFT 16.0f
#define NCHUNK 2       // split-K chunks over the 4096 keys
#define KTILES ((N_TOK / NCHUNK) / 32)   // 64 32-key tiles per chunk

__device__ __forceinline__ bf16x8 ld_frag(const u16* p) {
    return __builtin_bit_cast(bf16x8, *reinterpret_cast<const uint4*>(p));
}
__device__ __forceinline__ u16 f2bf(float x) {
    return __builtin_bit_cast(u16, __float2bfloat16(x));
}
__device__ __forceinline__ float bf2f(u16 u) {
    return __bfloat162float(__builtin_bit_cast(__hip_bfloat16, u));
}
__device__ __forceinline__ f32x16 mfma_b(bf16x8 a, bf16x8 b, f32x16 c) {
    return __builtin_amdgcn_mfma_f32_32x32x16_bf16(a, b, c, 0, 0, 0);
}
__device__ __forceinline__ f32x4 mfma16(bf16x8 a, bf16x8 b, f32x4 c) {
    return __builtin_amdgcn_mfma_f32_16x16x32_bf16(a, b, c, 0, 0, 0);
}
// async 16B/lane global -> LDS (LDS dest = wave-uniform base + lane*16)
__device__ __forceinline__ void gl_lds16(const u16* g, u16* l) {
    __builtin_amdgcn_global_load_lds(
        (const __attribute__((address_space(1))) void*)(g),
        (__attribute__((address_space(3))) void*)(l), 16, 0, 0);
}

// ---------------------------------------------------------------- prep
__global__ void prep_kernel(const float* __restrict__ t1, const float* __restrict__ t2,
                            const float* __restrict__ t1c,
                            const float* __restrict__ W1, const float* __restrict__ W2,
                            const float* __restrict__ W3,
                            const float* __restrict__ Wo1, const float* __restrict__ Wo2,
                            const float* __restrict__ Wo3,
                            u16* __restrict__ tA, u16* __restrict__ WqkvT,
                            u16* __restrict__ WoT)
{
    int idx = blockIdx.x * blockDim.x + threadIdx.x;
    const int TA_N = 3 * N_TOK * KPAD;
    const int WQ_N = 3 * OUT3 * KPAD;
    const int WO_N = 3 * DIMP * RDIM;
    if (idx < TA_N) {
        int m = idx / (N_TOK * KPAD);
        int rem = idx - m * (N_TOK * KPAD);
        int row = rem / KPAD;
        int col = rem - row * KPAD;
        const float* t = (m == 0) ? t1 : (m == 1) ? t2 : t1c;
        tA[idx] = (col < DIMF) ? f2bf(t[row * DIMF + col]) : (u16)0;
    } else if (idx < TA_N + WQ_N) {
        int i = idx - TA_N;
        int m = i / (OUT3 * KPAD);
        int rem = i - m * (OUT3 * KPAD);
        int n = rem / KPAD;
        int c = rem - n * KPAD;
        const float* W = (m == 0) ? W1 : (m == 1) ? W2 : W3;
        WqkvT[i] = (c < DIMF) ? f2bf(W[c * OUT3 + n]) : (u16)0;
    } else if (idx < TA_N + WQ_N + WO_N) {
        int i = idx - TA_N - WQ_N;
        int m = i / (DIMP * RDIM);
        int rem = i - m * (DIMP * RDIM);
        int n = rem / RDIM;
        int c = rem - n * RDIM;
        const float* W = (m == 0) ? Wo1 : (m == 1) ? Wo2 : Wo3;
        WoT[i] = (n < DIMF) ? f2bf(W[c * DIMF + n]) : (u16)0;
    }
}

// ---------------------------------------------------------------- QKV gemm
// R5: fragment-order global_load_lds staging, double buffer, 1 barrier/K-step.
__global__ __launch_bounds__(256, 2) void qkv_gemm(
    const u16* __restrict__ tA, const u16* __restrict__ WqkvT,
    const float* __restrict__ b1, const float* __restrict__ b2, const float* __restrict__ b3,
    u16* __restrict__ qbuf, u16* __restrict__ kbuf, u16* __restrict__ vT)
{
    const int mt = blockIdx.x, nt = blockIdx.y, mod = blockIdx.z;
    const u16* A = tA + mod * (N_TOK * KPAD);
    const u16* B = WqkvT + mod * (OUT3 * KPAD);
    const float* bias = (mod == 0) ? b1 : (mod == 1) ? b2 : b3;

    __shared__ alignas(16) u16 Fbuf[2][16 * 512];

    const int tid = threadIdx.x;
    const int lane = tid & 63;
    const int w = tid >> 6;
    const int wm = w & 1, wn = w >> 1;
    const int l31 = lane & 31, h = lane >> 5;

    auto stage = [&](int kt, u16* dst) {
#pragma unroll
        for (int fi = 0; fi < 4; fi++) {
            int f = w * 4 + fi;
            int rb = (f & 7) >> 1, kc = f & 1;
            const u16* src = (f < 8)
                ? &A[(mt * 128 + rb * 32 + l31) * KPAD + kt * 32 + kc * 16 + h * 8]
                : &B[(nt * 128 + rb * 32 + l31) * KPAD + kt * 32 + kc * 16 + h * 8];
            gl_lds16(src, dst + f * 512);
        }
    };

    f32x16 acc[2][2];
#pragma unroll
    for (int i = 0; i < 2; i++)
#pragma unroll
        for (int j = 0; j < 2; j++)
#pragma unroll
            for (int r = 0; r < 16; r++) acc[i][j][r] = 0.f;

    stage(0, Fbuf[0]);
    __syncthreads();   // tile 0 resident

    for (int kt = 0; kt < KPAD / 32; kt++) {
        const int p = kt & 1;
        if (kt + 1 < KPAD / 32) stage(kt + 1, Fbuf[p ^ 1]);
        const u16* FB = Fbuf[p];
#pragma unroll
        for (int kc = 0; kc < 2; kc++) {
            bf16x8 af[2], bfr[2];
#pragma unroll
            for (int mr = 0; mr < 2; mr++)
                af[mr] = ld_frag(&FB[((wm * 2 + mr) * 2 + kc) * 512 + lane * 8]);
#pragma unroll
            for (int nr = 0; nr < 2; nr++)
                bfr[nr] = ld_frag(&FB[(8 + (wn * 2 + nr) * 2 + kc) * 512 + lane * 8]);
#pragma unroll
            for (int mr = 0; mr < 2; mr++)
#pragma unroll
                for (int nr = 0; nr < 2; nr++)
                    acc[mr][nr] = mfma_b(af[mr], bfr[nr], acc[mr][nr]);
        }
        __syncthreads();
    }

    u16* qb = qbuf + mod * (N_TOK * OUTD);
    u16* kb = kbuf + mod * (N_TOK * OUTD);
    u16* vb = vT + mod * (OUTD * N_TOK);
#pragma unroll
    for (int mr = 0; mr < 2; mr++)
#pragma unroll
        for (int nr = 0; nr < 2; nr++)
#pragma unroll
            for (int r = 0; r < 16; r++) {
                int row = mt * 128 + wm * 64 + mr * 32 + (r & 3) + 8 * (r >> 2) + 4 * h;
                int col = nt * 128 + wn * 64 + nr * 32 + l31;
                u16 bv = f2bf(acc[mr][nr][r] + bias[col]);
                int cs = col >> 8, cc = col & 255;
                if (cs == 0)      qb[row * OUTD + cc] = bv;
                else if (cs == 1) kb[row * OUTD + cc] = bv;
                else              vb[cc * N_TOK + row] = bv;   // v transposed
            }
}

// ---------------------------------------------------------------- attention
// R8 = R7's occupancy unlock with its two measured bugs fixed.
// R7 post-mortem: occupancy 30% (thesis right) but (1) 16x16x16 PV is
// half-rate -> pipe-busy 43.5 -> 67.5 us; (2) V b64 reads = 2.6e7 bank
// conflicts. R8: 32-key tiles, 16 q/wave, ALL MFMAs full-rate 16x16x32
// (16 S + 16 PV per tile/wave), all LDS reads contiguous 1KB frags at
// lane*16B (0 conflicts).
// Key trick: MFMA contraction is order-invariant -> permute key-slot order
// on BOTH PV operands. K staged with pre-swizzled per-lane global row
// (row sl <-> key (sl>>2)*8 + c*4 + (sl&3), c = S-instr index). Then lane
// (sl,sg) ends up holding S/P for 8 CONSECUTIVE keys sg*8..+7 of q=sl:
// P packs into the PV B-operand with ZERO cross-lane ops, and V frags are
// 16B-contiguous gl_lds16 stages (lane -> vT[nb*16+sl][k0+sg*8..+8]).
// Resources: Oacc 64 + qf 32 + misc ~40 -> (256,3) = 3 waves/SIMD;
// LDS = K dbuf 32KB + V single 16KB = 48KB -> 3 blocks/CU; grid 64x6x2 =
// 768 = exactly 3x256, zero tail. V single-buffer costs 3 barriers/tile
// with counted vmcnt (R6-validated asm pattern); 3 independent blocks/CU
// cross-fill the barrier stalls. Per-wave loads/tile: 4 K + 4 V.
__global__ __launch_bounds__(256, 3) void attn_kernel(
    const u16* __restrict__ qbuf, const u16* __restrict__ kbuf,
    const u16* __restrict__ vT, u16* __restrict__ Opart, float* __restrict__ lpart)
{
    const int qt = blockIdx.x;   // 0..63  (64-row q tile)
    const int g  = blockIdx.y;   // 0..5
    const int c  = blockIdx.z;   // 0..NCHUNK-1
    const int kv = g >> 1;
    const int mn = (kv == 0) ? 1 : 0;
    const int mx = (kv == 2) ? 1 : 2;
    const int qm = (g & 1) ? mx : mn;

    const u16* Qg = qbuf + qm * (N_TOK * OUTD);
    const u16* Kg = kbuf + kv * (N_TOK * OUTD);
    const u16* Vg = vT + kv * (OUTD * N_TOK);
    u16* Op = Opart + ((size_t)(c * 6 + g) * N_TOK + qt * 64) * OUTD;
    float* lp = lpart + (c * 6 + g) * N_TOK + qt * 64;

    __shared__ alignas(16) u16 Kb[2][16 * 512];   // 32 KB (K double buffer)
    __shared__ alignas(16) u16 Vb[16 * 512];      // 16 KB (V single buffer)

    const int tid = threadIdx.x;
    const int lane = tid & 63;
    const int w = tid >> 6;           // 0..3
    const int sl = lane & 15, sg = lane >> 4;   // 16-lane group coords
    const int q0 = qt * 64 + w * 16;
    // pre-swizzled K row: S-instr cc covers keys (sl>>2)*8 + cc*4 + (sl&3)
    const int krow = (sl >> 2) * 8 + (sl & 3);

    // wave w stages K frags f = w*4 .. w*4+3 (f = cc*8 + j)
    auto stageK = [&](int k0, u16* dst) {
#pragma unroll
        for (int fi = 0; fi < 4; fi++) {
            int f = w * 4 + fi;
            int cc = f >> 3, j = f & 7;
            gl_lds16(&Kg[(k0 + krow + cc * 4) * OUTD + j * 32 + sg * 8],
                     dst + f * 512);
        }
    };
    // wave w stages V frags nb = w*4 .. w*4+3
    auto stageV = [&](int k0) {
#pragma unroll
        for (int fi = 0; fi < 4; fi++) {
            int nb = w * 4 + fi;
            gl_lds16(&Vg[(size_t)(nb * 16 + sl) * N_TOK + k0 + sg * 8],
                     Vb + nb * 512);
        }
    };

    const int k0base = c * (N_TOK / NCHUNK);

    // prologue: stage K tile 0; Q frags qf[j]: lane holds
    // Q[q0 + sl][j*32 + sg*8 .. +8]  (16x16x32 B-operand)
    stageK(k0base, Kb[0]);

    bf16x8 qf[8];
#pragma unroll
    for (int j = 0; j < 8; j++)
        qf[j] = ld_frag(&Qg[(q0 + sl) * OUTD + j * 32 + sg * 8]);

    f32x4 Oacc[16];
#pragma unroll
    for (int nb = 0; nb < 16; nb++)
#pragma unroll
        for (int r = 0; r < 4; r++) Oacc[nb][r] = 0.f;
    float lsum = 0.f;

    for (int kt = 0; kt < KTILES; kt++) {
        const int p = kt & 1;
        const int k0 = k0base + kt * 32;

        // queue entering iter: [K(t) 4]
        stageV(k0);                                  // +4 -> [K(t)4, V(t)4]
        if (kt + 1 < KTILES) {
            stageK(k0 + 32, Kb[p ^ 1]);              // +4 -> 12 outstanding
            asm volatile("s_waitcnt vmcnt(8)" ::: "memory");   // K(t) landed
        } else {
            asm volatile("s_waitcnt vmcnt(4)" ::: "memory");   // K(t) landed
        }
        __builtin_amdgcn_s_barrier();   // Kb[p] valid for all waves

        // S[cc] (keys (sl>>2)*8+cc*4+(sl&3)-swizzled 16k x 16q), 2 chains of 8
        const u16* KB = Kb[p];
        f32x4 S0, S1;
#pragma unroll
        for (int r = 0; r < 4; r++) { S0[r] = 0.f; S1[r] = 0.f; }
        __builtin_amdgcn_s_setprio(1);
#pragma unroll
        for (int j = 0; j < 8; j++) {
            bf16x8 kf0 = ld_frag(&KB[j * 512 + lane * 8]);
            bf16x8 kf1 = ld_frag(&KB[(8 + j) * 512 + lane * 8]);
            S0 = mfma16(kf0, qf[j], S0);
            S1 = mfma16(kf1, qf[j], S1);
        }
        __builtin_amdgcn_s_setprio(0);

        // P = exp(S - 16). Lane (sl,sg) rows: S0 -> keys sg*8+{0..3},
        // S1 -> keys sg*8+4+{0..3} (consecutive 8) for q = sl.
        float e0 = __expf(S0[0] - SHIFT), e1 = __expf(S0[1] - SHIFT);
        float e2 = __expf(S0[2] - SHIFT), e3 = __expf(S0[3] - SHIFT);
        float e4 = __expf(S1[0] - SHIFT), e5 = __expf(S1[1] - SHIFT);
        float e6 = __expf(S1[2] - SHIFT), e7 = __expf(S1[3] - SHIFT);
        lsum += ((e0 + e1) + (e2 + e3)) + ((e4 + e5) + (e6 + e7));
        uint4 bu;
        bu.x = (u32)f2bf(e0) | ((u32)f2bf(e1) << 16);
        bu.y = (u32)f2bf(e2) | ((u32)f2bf(e3) << 16);
        bu.z = (u32)f2bf(e4) | ((u32)f2bf(e5) << 16);
        bu.w = (u32)f2bf(e6) | ((u32)f2bf(e7) << 16);
        bf16x8 pb = __builtin_bit_cast(bf16x8, bu);   // PV B-operand, no repack

        // V(t) landed (K(t+1) may fly), then barrier -> Vb valid all waves
        if (kt + 1 < KTILES)
            asm volatile("s_waitcnt vmcnt(4)" ::: "memory");
        else
            asm volatile("s_waitcnt vmcnt(0)" ::: "memory");
        __builtin_amdgcn_s_barrier();

        // O[d][q] += V[d][k] P[k][q]: 16 independent full-rate 16x16x32
        __builtin_amdgcn_s_setprio(1);
#pragma unroll
        for (int nb = 0; nb < 16; nb++) {
            bf16x8 vf = ld_frag(&Vb[nb * 512 + lane * 8]);
            Oacc[nb] = mfma16(vf, pb, Oacc[nb]);
        }
        __builtin_amdgcn_s_setprio(0);
        __builtin_amdgcn_s_barrier();   // PV done all waves; Vb free
    }

    // l partials: lane covers keys sg*8..+7 for q=sl; reduce over sg groups
    lsum += __shfl_xor(lsum, 16, 64);
    lsum += __shfl_xor(lsum, 32, 64);
    if (lane < 16) lp[w * 16 + lane] = lsum;

    // transpose O^T -> [q][d] via wave-private scratch in Vb (dead now).
    // Oacc[nb][r] = O[d = nb*16 + sg*4 + r][q = sl].
    float* Tb = reinterpret_cast<float*>(&Vb[0]) + w * (16 * 17);
#pragma unroll
    for (int nb = 0; nb < 16; nb++) {
#pragma unroll
        for (int r = 0; r < 4; r++)
            Tb[(sg * 4 + r) * 17 + sl] = Oacc[nb][r];
        __builtin_amdgcn_s_waitcnt(0);  // lgkm drain before re-read (wave-private)
        int qq = lane >> 2, d4 = (lane & 3) * 4;
        float v0 = Tb[(d4 + 0) * 17 + qq];
        float v1 = Tb[(d4 + 1) * 17 + qq];
        float v2 = Tb[(d4 + 2) * 17 + qq];
        float v3 = Tb[(d4 + 3) * 17 + qq];
        uint2 sv;
        sv.x = (u32)f2bf(v0) | ((u32)f2bf(v1) << 16);
        sv.y = (u32)f2bf(v2) | ((u32)f2bf(v3) << 16);
        *reinterpret_cast<uint2*>(&Op[(w * 16 + qq) * OUTD + nb * 16 + d4]) = sv;
        __builtin_amdgcn_s_waitcnt(0);
    }
}

// ---------------------------------------------------------------- combine
// o = sum(O_c)/sum(l_c) + k_residual -> rbuf bf16 [qm][q][slot*256+d]
__global__ __launch_bounds__(256, 1) void combine_kernel(
    const u16* __restrict__ Opart, const float* __restrict__ lpart,
    const u16* __restrict__ kbuf, u16* __restrict__ rbuf)
{
    const int q = blockIdx.x;
    const int g = blockIdx.y;
    const int d = threadIdx.x;
    const int kv = g >> 1;
    const int mn = (kv == 0) ? 1 : 0;
    const int mx = (kv == 2) ? 1 : 2;
    const int qm = (g & 1) ? mx : mn;
    const int sm = (qm == 0) ? 1 : 0;
    const int slot = (kv == sm) ? 0 : 1;

    float o = 0.f, l = 0.f;
#pragma unroll
    for (int c = 0; c < NCHUNK; c++) {
        o += bf2f(Opart[((size_t)(c * 6 + g) * N_TOK + q) * OUTD + d]);
        l += lpart[(c * 6 + g) * N_TOK + q];
    }
    float res = o / l + bf2f(kbuf[qm * (N_TOK * OUTD) + q * OUTD + d]);
    rbuf[qm * (size_t)(N_TOK * RDIM) + q * RDIM + slot * OUTD + d] = f2bf(res);
}

// ---------------------------------------------------------------- out proj
// R5: fragment-order gl_lds staging; B = WoT padded to DIMP=640 rows.
__global__ __launch_bounds__(256, 2) void proj_gemm(
    const u16* __restrict__ rbuf, const u16* __restrict__ WoT,
    const float* __restrict__ bo1, const float* __restrict__ bo2, const float* __restrict__ bo3,
    const float* __restrict__ t1, const float* __restrict__ t2, const float* __restrict__ t1c,
    float* __restrict__ feat)
{
    const int mt = blockIdx.x, nt = blockIdx.y, mod = blockIdx.z;
    const u16* A = rbuf + mod * (N_TOK * RDIM);
    const u16* B = WoT + mod * (DIMP * RDIM);
    const float* bias = (mod == 0) ? bo1 : (mod == 1) ? bo2 : bo3;
    const float* tres = (mod == 0) ? t1 : (mod == 1) ? t2 : t1c;

    __shared__ alignas(16) u16 Fbuf[2][16 * 512];

    const int tid = threadIdx.x;
    const int lane = tid & 63;
    const int w = tid >> 6;
    const int wm = w & 1, wn = w >> 1;
    const int l31 = lane & 31, h = lane >> 5;

    auto stage = [&](int kt, u16* dst) {
#pragma unroll
        for (int fi = 0; fi < 4; fi++) {
            int f = w * 4 + fi;
            int rb = (f & 7) >> 1, kc = f & 1;
            const u16* src = (f < 8)
                ? &A[(mt * 128 + rb * 32 + l31) * RDIM + kt * 32 + kc * 16 + h * 8]
                : &B[(nt * 128 + rb * 32 + l31) * RDIM + kt * 32 + kc * 16 + h * 8];
            gl_lds16(src, dst + f * 512);
        }
    };

    f32x16 acc[2][2];
#pragma unroll
    for (int i = 0; i < 2; i++)
#pragma unroll
        for (int j = 0; j < 2; j++)
#pragma unroll
            for (int r = 0; r < 16; r++) acc[i][j][r] = 0.f;

    stage(0, Fbuf[0]);
    __syncthreads();

    for (int kt = 0; kt < RDIM / 32; kt++) {
        const int p = kt & 1;
        if (kt + 1 < RDIM / 32) stage(kt + 1, Fbuf[p ^ 1]);
        const u16* FB = Fbuf[p];
#pragma unroll
        for (int kc = 0; kc < 2; kc++) {
            bf16x8 af[2], bfr[2];
#pragma unroll
            for (int mr = 0; mr < 2; mr++)
                af[mr] = ld_frag(&FB[((wm * 2 + mr) * 2 + kc) * 512 + lane * 8]);
#pragma unroll
            for (int nr = 0; nr < 2; nr++)
                bfr[nr] = ld_frag(&FB[(8 + (wn * 2 + nr) * 2 + kc) * 512 + lane * 8]);
#pragma unroll
            for (int mr = 0; mr < 2; mr++)
#pragma unroll
                for (int nr = 0; nr < 2; nr++)
                    acc[mr][nr] = mfma_b(af[mr], bfr[nr], acc[mr][nr]);
        }
        __syncthreads();
    }

#pragma unroll
    for (int mr = 0; mr < 2; mr++)
#pragma unroll
        for (int nr = 0; nr < 2; nr++)
#pragma unroll
            for (int r = 0; r < 16; r++) {
                int row = mt * 128 + wm * 64 + mr * 32 + (r & 3) + 8 * (r >> 2) + 4 * h;
                int col = nt * 128 + wn * 64 + nr * 32 + l31;
                if (col < DIMF) {
                    float v = acc[mr][nr][r] + bias[col] + tres[row * DIMF + col];
                    feat[row * FDIM + mod * DIMF + col] = v;
                }
            }
}

// ---------------------------------------------------------------- LN + head
__global__ __launch_bounds__(256, 1) void ln_head(
    const float* __restrict__ feat, const float* __restrict__ gam,
    const float* __restrict__ bet, const float* __restrict__ Wh,
    const float* __restrict__ bh, float* __restrict__ out)
{
    const int row = blockIdx.x;
    const float* x = feat + row * FDIM;
    const int tid = threadIdx.x;
    float v[7];
    float s = 0.f, ss = 0.f;
#pragma unroll
    for (int i = 0; i < 7; i++) {
        int idx = tid + i * 256;
        float val = (idx < FDIM) ? x[idx] : 0.f;
        v[i] = val; s += val; ss += val * val;
    }
#pragma unroll
    for (int m = 1; m < 64; m <<= 1) { s += __shfl_xor(s, m, 64); ss += __shfl_xor(ss, m, 64); }
    __shared__ float red[8];
    const int w = tid >> 6, lane = tid & 63;
    if (lane == 0) { red[w] = s; red[4 + w] = ss; }
    __syncthreads();
    s = red[0] + red[1] + red[2] + red[3];
    ss = red[4] + red[5] + red[6] + red[7];
    const float mu = s / (float)FDIM;
    const float var = ss / (float)FDIM - mu * mu;
    const float rstd = rsqrtf(var + 1e-5f);
    float a0 = 0.f, a1 = 0.f;
#pragma unroll
    for (int i = 0; i < 7; i++) {
        int idx = tid + i * 256;
        if (idx < FDIM) {
            float nv = (v[i] - mu) * rstd * gam[idx] + bet[idx];
            a0 += nv * Wh[idx * 2];
            a1 += nv * Wh[idx * 2 + 1];
        }
    }
#pragma unroll
    for (int m = 1; m < 64; m <<= 1) { a0 += __shfl_xor(a0, m, 64); a1 += __shfl_xor(a1, m, 64); }
    __shared__ float red2[8];
    if (lane == 0) { red2[w] = a0; red2[4 + w] = a1; }
    __syncthreads();
    if (tid == 0) {
        out[row * 2 + 0] = red2[0] + red2[1] + red2[2] + red2[3] + bh[0];
        out[row * 2 + 1] = red2[4] + red2[5] + red2[6] + red2[7] + bh[1];
    }
}

// ---------------------------------------------------------------- launch
extern "C" void kernel_launch(void* const* d_in, const int* in_sizes, int n_in,
                              void* d_out, int out_size, void* d_ws, size_t ws_size,
                              hipStream_t stream)
{
    const float* t1    = (const float*)d_in[0];
    const float* t2    = (const float*)d_in[1];
    const float* t1c   = (const float*)d_in[2];
    const float* Wqkv1 = (const float*)d_in[3];
    const float* bqkv1 = (const float*)d_in[4];
    const float* Wqkv2 = (const float*)d_in[5];
    const float* bqkv2 = (const float*)d_in[6];
    const float* Wqkv3 = (const float*)d_in[7];
    const float* bqkv3 = (const float*)d_in[8];
    const float* Wo1   = (const float*)d_in[9];
    const float* bo1   = (const float*)d_in[10];
    const float* Wo2   = (const float*)d_in[11];
    const float* bo2   = (const float*)d_in[12];
    const float* Wo3   = (const float*)d_in[13];
    const float* bo3   = (const float*)d_in[14];
    const float* ln_g  = (const float*)d_in[15];
    const float* ln_b  = (const float*)d_in[16];
    const float* Wh    = (const float*)d_in[17];
    const float* bh    = (const float*)d_in[18];

    char* ws = (char*)d_ws;
    size_t off = 0;
    u16* tA    = (u16*)(ws + off); off += (size_t)3 * N_TOK * KPAD * 2;
    u16* WqkvT = (u16*)(ws + off); off += (size_t)3 * OUT3 * KPAD * 2;
    u16* WoT   = (u16*)(ws + off); off += (size_t)3 * DIMP * RDIM * 2;
    u16* qbuf  = (u16*)(ws + off); off += (size_t)3 * N_TOK * OUTD * 2;
    u16* kbuf  = (u16*)(ws + off); off += (size_t)3 * N_TOK * OUTD * 2;
    u16* vT    = (u16*)(ws + off); off += (size_t)3 * OUTD * N_TOK * 2;
    u16* rbuf  = (u16*)(ws + off); off += (size_t)3 * N_TOK * RDIM * 2;
    u16* Opart = (u16*)(ws + off); off += (size_t)NCHUNK * 6 * N_TOK * OUTD * 2;
    float* lpart = (float*)(ws + off); off += (size_t)NCHUNK * 6 * N_TOK * 4;

    float* out  = (float*)d_out;
    float* feat = out + N_TOK * 2;

    const int prep_total = 3 * N_TOK * KPAD + 3 * OUT3 * KPAD + 3 * DIMP * RDIM;
    prep_kernel<<<(prep_total + 255) / 256, 256, 0, stream>>>(
        t1, t2, t1c, Wqkv1, Wqkv2, Wqkv3, Wo1, Wo2, Wo3, tA, WqkvT, WoT);

    qkv_gemm<<<dim3(32, 6, 3), 256, 0, stream>>>(
        tA, WqkvT, bqkv1, bqkv2, bqkv3, qbuf, kbuf, vT);

    attn_kernel<<<dim3(64, 6, NCHUNK), 256, 0, stream>>>(qbuf, kbuf, vT, Opart, lpart);

    combine_kernel<<<dim3(N_TOK, 6), 256, 0, stream>>>(Opart, lpart, kbuf, rbuf);

    proj_gemm<<<dim3(32, 5, 3), 256, 0, stream>>>(
        rbuf, WoT, bo1, bo2, bo3, t1, t2, t1c, feat);

    ln_head<<<4096, 256, 0, stream>>>(feat, ln_g, ln_b, Wh, bh, out);
}

// Round 9
// 323.417 us; speedup vs baseline: 1.2862x; 1.2862x over previous
//
#include <hip/hip_runtime.h>
#include <hip/hip_bf16.h>

typedef unsigned short u16;
typedef unsigned int u32;
typedef __attribute__((ext_vector_type(8))) __bf16 bf16x8;
typedef __attribute__((ext_vector_type(4))) float f32x4;
typedef __attribute__((ext_vector_type(16))) float f32x16;

#define N_TOK 4096
#define DIMF  514
#define KPAD  544      // 17*32, zero-padded K for QKV gemm
#define OUT3  768
#define OUTD  256
#define RDIM  512
#define DIMP  640      // 5*128, zero-padded Wo output-dim for proj staging
#define FDIM  1542
#define SHIFT 16.0f
#define NCHUNK 4       // split-K chunks over the 4096 keys (R4 attn)
#define KTILES ((N_TOK / NCHUNK) / 32)   // 32-key tiles per chunk

__device__ __forceinline__ bf16x8 ld_frag(const u16* p) {
    return __builtin_bit_cast(bf16x8, *reinterpret_cast<const uint4*>(p));
}
__device__ __forceinline__ u16 f2bf(float x) {
    return __builtin_bit_cast(u16, __float2bfloat16(x));
}
__device__ __forceinline__ float bf2f(u16 u) {
    return __bfloat162float(__builtin_bit_cast(__hip_bfloat16, u));
}
__device__ __forceinline__ f32x16 mfma_b(bf16x8 a, bf16x8 b, f32x16 c) {
    return __builtin_amdgcn_mfma_f32_32x32x16_bf16(a, b, c, 0, 0, 0);
}
__device__ __forceinline__ f32x4 mfma16(bf16x8 a, bf16x8 b, f32x4 c) {
    return __builtin_amdgcn_mfma_f32_16x16x32_bf16(a, b, c, 0, 0, 0);
}
// async 16B/lane global -> LDS (LDS dest = wave-uniform base + lane*16)
__device__ __forceinline__ void gl_lds16(const u16* g, u16* l) {
    __builtin_amdgcn_global_load_lds(
        (const __attribute__((address_space(1))) void*)(g),
        (__attribute__((address_space(3))) void*)(l), 16, 0, 0);
}

// ---------------------------------------------------------------- prep (R9)
// Split into 3 coalesced kernels. Old single prep had fully uncoalesced
// weight reads (W[c*OUT3+n], c fastest -> 3KB-strided 4B loads, 16x fetch
// amplification) and 2B/lane tA writes.

// tA: cast+pad t -> bf16 [3][4096][544]. Thread = (row, col-pair):
// 8B coalesced f32 reads, 4B coalesced u32 stores.
__global__ void prep_ta(const float* __restrict__ t1, const float* __restrict__ t2,
                        const float* __restrict__ t1c, u16* __restrict__ tA)
{
    const int PER_M = N_TOK * (KPAD / 2);
    int idx = blockIdx.x * blockDim.x + threadIdx.x;
    if (idx >= 3 * PER_M) return;
    int m = idx / PER_M;
    int rem = idx - m * PER_M;
    int row = rem / (KPAD / 2);
    int cp = rem - row * (KPAD / 2);
    int c0 = cp * 2;
    const float* t = (m == 0) ? t1 : (m == 1) ? t2 : t1c;
    u16 a = (c0 < DIMF) ? f2bf(t[row * DIMF + c0]) : (u16)0;
    u16 b = (c0 + 1 < DIMF) ? f2bf(t[row * DIMF + c0 + 1]) : (u16)0;
    *reinterpret_cast<u32*>(&tA[((size_t)m * N_TOK + row) * KPAD + c0]) =
        (u32)a | ((u32)b << 16);
}

// WqkvT: [3][768 n][544 c] = W[c][n] (c<514, else 0). LDS-tiled transpose:
// reads coalesced along n, writes coalesced along c.
__global__ __launch_bounds__(256) void prep_wq(
    const float* __restrict__ W1, const float* __restrict__ W2,
    const float* __restrict__ W3, u16* __restrict__ WqkvT)
{
    const int nt = blockIdx.x, ct = blockIdx.y, m = blockIdx.z;
    const float* W = (m == 0) ? W1 : (m == 1) ? W2 : W3;
    __shared__ float Ts[32][33];
    const int tid = threadIdx.x;
#pragma unroll
    for (int p = 0; p < 4; p++) {
        int c_loc = p * 8 + (tid >> 5);
        int n_loc = tid & 31;
        int c = ct * 32 + c_loc, n = nt * 32 + n_loc;
        Ts[c_loc][n_loc] = (c < DIMF) ? W[c * OUT3 + n] : 0.f;
    }
    __syncthreads();
#pragma unroll
    for (int p = 0; p < 4; p++) {
        int n_loc = p * 8 + (tid >> 5);
        int c_loc = tid & 31;
        WqkvT[((size_t)m * OUT3 + nt * 32 + n_loc) * KPAD + ct * 32 + c_loc] =
            f2bf(Ts[c_loc][n_loc]);
    }
}

// WoT: [3][640 n][512 c] = Wo[c][n] (n<514, else 0). Same tiled transpose.
__global__ __launch_bounds__(256) void prep_wo(
    const float* __restrict__ Wo1, const float* __restrict__ Wo2,
    const float* __restrict__ Wo3, u16* __restrict__ WoT)
{
    const int nt = blockIdx.x, ct = blockIdx.y, m = blockIdx.z;
    const float* W = (m == 0) ? Wo1 : (m == 1) ? Wo2 : Wo3;
    __shared__ float Ts[32][33];
    const int tid = threadIdx.x;
#pragma unroll
    for (int p = 0; p < 4; p++) {
        int c_loc = p * 8 + (tid >> 5);
        int n_loc = tid & 31;
        int c = ct * 32 + c_loc, n = nt * 32 + n_loc;
        Ts[c_loc][n_loc] = (n < DIMF) ? W[c * DIMF + n] : 0.f;
    }
    __syncthreads();
#pragma unroll
    for (int p = 0; p < 4; p++) {
        int n_loc = p * 8 + (tid >> 5);
        int c_loc = tid & 31;
        WoT[((size_t)m * DIMP + nt * 32 + n_loc) * RDIM + ct * 32 + c_loc] =
            f2bf(Ts[c_loc][n_loc]);
    }
}

// ---------------------------------------------------------------- QKV gemm
// R5: fragment-order global_load_lds staging, double buffer, 1 barrier/K-step.
__global__ __launch_bounds__(256, 2) void qkv_gemm(
    const u16* __restrict__ tA, const u16* __restrict__ WqkvT,
    const float* __restrict__ b1, const float* __restrict__ b2, const float* __restrict__ b3,
    u16* __restrict__ qbuf, u16* __restrict__ kbuf, u16* __restrict__ vT)
{
    const int mt = blockIdx.x, nt = blockIdx.y, mod = blockIdx.z;
    const u16* A = tA + mod * (N_TOK * KPAD);
    const u16* B = WqkvT + mod * (OUT3 * KPAD);
    const float* bias = (mod == 0) ? b1 : (mod == 1) ? b2 : b3;

    __shared__ alignas(16) u16 Fbuf[2][16 * 512];

    const int tid = threadIdx.x;
    const int lane = tid & 63;
    const int w = tid >> 6;
    const int wm = w & 1, wn = w >> 1;
    const int l31 = lane & 31, h = lane >> 5;

    auto stage = [&](int kt, u16* dst) {
#pragma unroll
        for (int fi = 0; fi < 4; fi++) {
            int f = w * 4 + fi;
            int rb = (f & 7) >> 1, kc = f & 1;
            const u16* src = (f < 8)
                ? &A[(mt * 128 + rb * 32 + l31) * KPAD + kt * 32 + kc * 16 + h * 8]
                : &B[(nt * 128 + rb * 32 + l31) * KPAD + kt * 32 + kc * 16 + h * 8];
            gl_lds16(src, dst + f * 512);
        }
    };

    f32x16 acc[2][2];
#pragma unroll
    for (int i = 0; i < 2; i++)
#pragma unroll
        for (int j = 0; j < 2; j++)
#pragma unroll
            for (int r = 0; r < 16; r++) acc[i][j][r] = 0.f;

    stage(0, Fbuf[0]);
    __syncthreads();   // tile 0 resident

    for (int kt = 0; kt < KPAD / 32; kt++) {
        const int p = kt & 1;
        if (kt + 1 < KPAD / 32) stage(kt + 1, Fbuf[p ^ 1]);
        const u16* FB = Fbuf[p];
#pragma unroll
        for (int kc = 0; kc < 2; kc++) {
            bf16x8 af[2], bfr[2];
#pragma unroll
            for (int mr = 0; mr < 2; mr++)
                af[mr] = ld_frag(&FB[((wm * 2 + mr) * 2 + kc) * 512 + lane * 8]);
#pragma unroll
            for (int nr = 0; nr < 2; nr++)
                bfr[nr] = ld_frag(&FB[(8 + (wn * 2 + nr) * 2 + kc) * 512 + lane * 8]);
#pragma unroll
            for (int mr = 0; mr < 2; mr++)
#pragma unroll
                for (int nr = 0; nr < 2; nr++)
                    acc[mr][nr] = mfma_b(af[mr], bfr[nr], acc[mr][nr]);
        }
        __syncthreads();
    }

    u16* qb = qbuf + mod * (N_TOK * OUTD);
    u16* kb = kbuf + mod * (N_TOK * OUTD);
    u16* vb = vT + mod * (OUTD * N_TOK);
#pragma unroll
    for (int mr = 0; mr < 2; mr++)
#pragma unroll
        for (int nr = 0; nr < 2; nr++)
#pragma unroll
            for (int r = 0; r < 16; r++) {
                int row = mt * 128 + wm * 64 + mr * 32 + (r & 3) + 8 * (r >> 2) + 4 * h;
                int col = nt * 128 + wn * 64 + nr * 32 + l31;
                u16 bv = f2bf(acc[mr][nr][r] + bias[col]);
                int cs = col >> 8, cc = col & 255;
                if (cs == 0)      qb[row * OUTD + cc] = bv;
                else if (cs == 1) kb[row * OUTD + cc] = bv;
                else              vb[cc * N_TOK + row] = bv;   // v transposed
            }
}

// ---------------------------------------------------------------- attention
// R9 = exact revert to R4 (best measured: 138.7 us, MfmaUtil 32).
// Verdict after R6/R7/R8: every occupancy-raising restructure (split-D 305,
// 16q half-rate 226, 16q full-rate+swizzle 227) loses to this structure's
// 2-waves/SIMD + full double-buffer + 1 barrier/tile. The V single-buffer
// variants expose V latency with only the S-phase as cover; phase-locked
// sibling blocks can't cross-fill. DO NOT touch without new evidence.
// Structure: 4 waves, 128 q rows (32/wave); waves 0/1 stage K frags, 2/3
// stage V frags (frag order, gl_lds16); S as four 16x16x32 quadrant MFMAs
// (4 indep chains of 8, same 16 acc regs); 4x permlane16_swap repack; PV as
// 16x 32x32x16 with 8 indep chains. 128 VGPR + 128 AGPR = the full pool at
// 2 waves/SIMD (R1: any net register -> spill catastrophe).
__global__ __launch_bounds__(256, 2) void attn_kernel(
    const u16* __restrict__ qbuf, const u16* __restrict__ kbuf,
    const u16* __restrict__ vT, u16* __restrict__ Opart, float* __restrict__ lpart)
{
    const int qt = blockIdx.x;   // 0..31  (128-row q tile)
    const int g  = blockIdx.y;   // 0..5
    const int c  = blockIdx.z;   // 0..NCHUNK-1
    const int kv = g >> 1;
    const int mn = (kv == 0) ? 1 : 0;
    const int mx = (kv == 2) ? 1 : 2;
    const int qm = (g & 1) ? mx : mn;

    const u16* Qg = qbuf + qm * (N_TOK * OUTD);
    const u16* Kg = kbuf + kv * (N_TOK * OUTD);
    const u16* Vg = vT + kv * (OUTD * N_TOK);
    u16* Op = Opart + ((size_t)(c * 6 + g) * N_TOK + qt * 128) * OUTD;
    float* lp = lpart + (c * 6 + g) * N_TOK + qt * 128;

    // 2 buffers x 32 frags x 512 u16 (1KB per frag: 64 lanes x 16B)
    __shared__ alignas(16) u16 Fbuf[2][32 * 512];

    const int tid = threadIdx.x;
    const int lane = tid & 63;
    const int w = tid >> 6;           // 0..3
    const int l31 = lane & 31, h = lane >> 5;
    const int sl = lane & 15, sg = lane >> 4;   // 16-lane group coords
    const int q0 = qt * 128 + w * 32;

    // ---- stage helper: wave w stages frags 8w..8w+7 of tile at k0.
    // K frag f = kh*8 + j (kh = w for w<2): lane l fetches
    //   K[k0 + kh*16 + (l&15)][j*32 + (l>>4)*8 .. +8]   (16x16x32 A-operand)
    auto stage = [&](int k0, u16* dst) {
        if (w < 2) {
#pragma unroll
            for (int fi = 0; fi < 8; fi++) {
                gl_lds16(&Kg[(k0 + w * 16 + sl) * OUTD + fi * 32 + sg * 8],
                         dst + (w * 8 + fi) * 512);
            }
        } else {
#pragma unroll
            for (int fi = 0; fi < 8; fi++) {
                int f = (w - 2) * 8 + fi;           // 0..15
                int nb = f >> 1, half = f & 1;
                gl_lds16(&Vg[(nb * 32 + l31) * N_TOK + k0 + half * 16 + h * 8],
                         dst + (16 + f) * 512);
            }
        }
    };

    const int k0base = c * (N_TOK / NCHUNK);

    // prologue: stage tile 0, load Q frags (16x16x32 B-operand layout):
    // qf[2*j+qh]: lane l holds Q[q0 + qh*16 + (l&15)][j*32 + (l>>4)*8 ..+8]
    stage(k0base, Fbuf[0]);

    bf16x8 qf[16];
#pragma unroll
    for (int j = 0; j < 8; j++)
#pragma unroll
        for (int qh = 0; qh < 2; qh++)
            qf[2 * j + qh] = ld_frag(&Qg[(q0 + qh * 16 + sl) * OUTD + j * 32 + sg * 8]);

    f32x16 Oacc[8];
#pragma unroll
    for (int nb = 0; nb < 8; nb++)
#pragma unroll
        for (int r = 0; r < 16; r++) Oacc[nb][r] = 0.f;
    float lsA0 = 0.f, lsA1 = 0.f;   // per-qh column-sum accumulators

    __syncthreads();   // drains vmcnt: tile 0 resident

    for (int kt = 0; kt < KTILES; kt++) {
        const int p = kt & 1;
        if (kt + 1 < KTILES) stage(k0base + (kt + 1) * 32, Fbuf[p ^ 1]);
        const u16* FB = Fbuf[p];

        // S quadrants: S[kh][qh] (16k x 16q each), 4 independent chains of 8.
        // D layout: col q = (l&15), row k = (l>>4)*4 + r  (within quadrant).
        f32x4 Sq[2][2];
#pragma unroll
        for (int a = 0; a < 2; a++)
#pragma unroll
            for (int b = 0; b < 2; b++)
#pragma unroll
                for (int r = 0; r < 4; r++) Sq[a][b][r] = 0.f;
        __builtin_amdgcn_s_setprio(1);
#pragma unroll
        for (int j = 0; j < 8; j++) {
            bf16x8 kf0 = ld_frag(&FB[j * 512 + lane * 8]);         // kh=0
            bf16x8 kf1 = ld_frag(&FB[(8 + j) * 512 + lane * 8]);   // kh=1
            Sq[0][0] = mfma16(kf0, qf[2 * j], Sq[0][0]);
            Sq[0][1] = mfma16(kf0, qf[2 * j + 1], Sq[0][1]);
            Sq[1][0] = mfma16(kf1, qf[2 * j], Sq[1][0]);
            Sq[1][1] = mfma16(kf1, qf[2 * j + 1], Sq[1][1]);
        }
        __builtin_amdgcn_s_setprio(0);

        // P = exp(S - 16); pack to bf16 pairs pk[qh][kh][pair]
        u32 pk[2][2][2];
#pragma unroll
        for (int kh = 0; kh < 2; kh++)
#pragma unroll
            for (int qh = 0; qh < 2; qh++) {
                float e0 = __expf(Sq[kh][qh][0] - SHIFT);
                float e1 = __expf(Sq[kh][qh][1] - SHIFT);
                float e2 = __expf(Sq[kh][qh][2] - SHIFT);
                float e3 = __expf(Sq[kh][qh][3] - SHIFT);
                if (qh == 0) lsA0 += (e0 + e1) + (e2 + e3);
                else         lsA1 += (e0 + e1) + (e2 + e3);
                pk[qh][kh][0] = (u32)f2bf(e0) | ((u32)f2bf(e1) << 16);
                pk[qh][kh][1] = (u32)f2bf(e2) | ((u32)f2bf(e3) << 16);
            }

        // Quadrant -> 32x32 B-operand repack, 4 swaps total.
        asm volatile("v_permlane16_swap_b32 %0, %1" : "+v"(pk[0][0][0]), "+v"(pk[1][0][0]));
        asm volatile("v_permlane16_swap_b32 %0, %1" : "+v"(pk[0][0][1]), "+v"(pk[1][0][1]));
        asm volatile("v_permlane16_swap_b32 %0, %1" : "+v"(pk[0][1][0]), "+v"(pk[1][1][0]));
        asm volatile("v_permlane16_swap_b32 %0, %1" : "+v"(pk[0][1][1]), "+v"(pk[1][1][1]));
        uint4 b0, b1;
        b0.x = pk[0][0][0]; b0.y = pk[0][0][1]; b0.z = pk[1][0][0]; b0.w = pk[1][0][1];
        b1.x = pk[0][1][0]; b1.y = pk[0][1][1]; b1.z = pk[1][1][0]; b1.w = pk[1][1][1];
        bf16x8 pb0 = __builtin_bit_cast(bf16x8, b0);
        bf16x8 pb1 = __builtin_bit_cast(bf16x8, b1);

        // O^T[d][q] += V^T[d][k] P^T[k][q]   (8 independent chains)
        __builtin_amdgcn_s_setprio(1);
#pragma unroll
        for (int nb = 0; nb < 8; nb++) {
            bf16x8 vf0 = ld_frag(&FB[(16 + 2 * nb) * 512 + lane * 8]);
            bf16x8 vf1 = ld_frag(&FB[(17 + 2 * nb) * 512 + lane * 8]);
            Oacc[nb] = mfma_b(vf0, pb0, Oacc[nb]);
            Oacc[nb] = mfma_b(vf1, pb1, Oacc[nb]);
        }
        __builtin_amdgcn_s_setprio(0);
        __syncthreads();   // waves done with FB; tile kt+1 loads drained
    }

    // l partials: total for q = (l&15) in qh-half; reduce across 16-lane groups
    lsA0 += __shfl_xor(lsA0, 16, 64);
    lsA0 += __shfl_xor(lsA0, 32, 64);
    lsA1 += __shfl_xor(lsA1, 16, 64);
    lsA1 += __shfl_xor(lsA1, 32, 64);
    if (lane < 16)      lp[w * 32 + lane] = lsA0;
    else if (lane < 32) lp[w * 32 + lane] = lsA1;

    // transpose O^T -> [q][d] through wave-private LDS scratch, store bf16
    float* Tb = reinterpret_cast<float*>(&Fbuf[0][0]) + w * (32 * 33);
#pragma unroll
    for (int nb = 0; nb < 8; nb++) {
#pragma unroll
        for (int r = 0; r < 16; r++)
            Tb[((r & 3) + 8 * (r >> 2) + 4 * h) * 33 + l31] = Oacc[nb][r];
        __builtin_amdgcn_s_waitcnt(0);  // lgkm drain before re-read (wave-private)
#pragma unroll
        for (int qq = 0; qq < 16; qq++) {
            float v = Tb[l31 * 33 + qq * 2 + h];
            Op[(w * 32 + qq * 2 + h) * OUTD + nb * 32 + l31] = f2bf(v);
        }
        __builtin_amdgcn_s_waitcnt(0);
    }
}

// ---------------------------------------------------------------- combine
// R9: vectorized. 4 q rows per block, uint2 (4x u16) loads/stores.
// o = sum(O_c)/sum(l_c) + k_residual -> rbuf bf16 [qm][q][slot*256+d]
__global__ __launch_bounds__(256, 1) void combine_kernel(
    const u16* __restrict__ Opart, const float* __restrict__ lpart,
    const u16* __restrict__ kbuf, u16* __restrict__ rbuf)
{
    const int g = blockIdx.y;
    const int tid = threadIdx.x;
    const int q = blockIdx.x * 4 + (tid >> 6);
    const int d4 = (tid & 63) * 4;
    const int kv = g >> 1;
    const int mn = (kv == 0) ? 1 : 0;
    const int mx = (kv == 2) ? 1 : 2;
    const int qm = (g & 1) ? mx : mn;
    const int sm = (qm == 0) ? 1 : 0;
    const int slot = (kv == sm) ? 0 : 1;

    float o[4] = {0.f, 0.f, 0.f, 0.f};
    float l = 0.f;
#pragma unroll
    for (int c = 0; c < NCHUNK; c++) {
        uint2 ov = *reinterpret_cast<const uint2*>(
            &Opart[((size_t)(c * 6 + g) * N_TOK + q) * OUTD + d4]);
        o[0] += bf2f((u16)(ov.x & 0xffff));
        o[1] += bf2f((u16)(ov.x >> 16));
        o[2] += bf2f((u16)(ov.y & 0xffff));
        o[3] += bf2f((u16)(ov.y >> 16));
        l += lpart[(c * 6 + g) * N_TOK + q];
    }
    uint2 kvv = *reinterpret_cast<const uint2*>(
        &kbuf[(size_t)qm * (N_TOK * OUTD) + q * OUTD + d4]);
    float rl = 1.f / l;
    u16 r0 = f2bf(o[0] * rl + bf2f((u16)(kvv.x & 0xffff)));
    u16 r1 = f2bf(o[1] * rl + bf2f((u16)(kvv.x >> 16)));
    u16 r2 = f2bf(o[2] * rl + bf2f((u16)(kvv.y & 0xffff)));
    u16 r3 = f2bf(o[3] * rl + bf2f((u16)(kvv.y >> 16)));
    uint2 sv;
    sv.x = (u32)r0 | ((u32)r1 << 16);
    sv.y = (u32)r2 | ((u32)r3 << 16);
    *reinterpret_cast<uint2*>(
        &rbuf[(size_t)qm * (N_TOK * RDIM) + q * RDIM + slot * OUTD + d4]) = sv;
}

// ---------------------------------------------------------------- out proj
// R5: fragment-order gl_lds staging; B = WoT padded to DIMP=640 rows.
__global__ __launch_bounds__(256, 2) void proj_gemm(
    const u16* __restrict__ rbuf, const u16* __restrict__ WoT,
    const float* __restrict__ bo1, const float* __restrict__ bo2, const float* __restrict__ bo3,
    const float* __restrict__ t1, const float* __restrict__ t2, const float* __restrict__ t1c,
    float* __restrict__ feat)
{
    const int mt = blockIdx.x, nt = blockIdx.y, mod = blockIdx.z;
    const u16* A = rbuf + mod * (N_TOK * RDIM);
    const u16* B = WoT + mod * (DIMP * RDIM);
    const float* bias = (mod == 0) ? bo1 : (mod == 1) ? bo2 : bo3;
    const float* tres = (mod == 0) ? t1 : (mod == 1) ? t2 : t1c;

    __shared__ alignas(16) u16 Fbuf[2][16 * 512];

    const int tid = threadIdx.x;
    const int lane = tid & 63;
    const int w = tid >> 6;
    const int wm = w & 1, wn = w >> 1;
    const int l31 = lane & 31, h = lane >> 5;

    auto stage = [&](int kt, u16* dst) {
#pragma unroll
        for (int fi = 0; fi < 4; fi++) {
            int f = w * 4 + fi;
            int rb = (f & 7) >> 1, kc = f & 1;
            const u16* src = (f < 8)
                ? &A[(mt * 128 + rb * 32 + l31) * RDIM + kt * 32 + kc * 16 + h * 8]
                : &B[(nt * 128 + rb * 32 + l31) * RDIM + kt * 32 + kc * 16 + h * 8];
            gl_lds16(src, dst + f * 512);
        }
    };

    f32x16 acc[2][2];
#pragma unroll
    for (int i = 0; i < 2; i++)
#pragma unroll
        for (int j = 0; j < 2; j++)
#pragma unroll
            for (int r = 0; r < 16; r++) acc[i][j][r] = 0.f;

    stage(0, Fbuf[0]);
    __syncthreads();

    for (int kt = 0; kt < RDIM / 32; kt++) {
        const int p = kt & 1;
        if (kt + 1 < RDIM / 32) stage(kt + 1, Fbuf[p ^ 1]);
        const u16* FB = Fbuf[p];
#pragma unroll
        for (int kc = 0; kc < 2; kc++) {
            bf16x8 af[2], bfr[2];
#pragma unroll
            for (int mr = 0; mr < 2; mr++)
                af[mr] = ld_frag(&FB[((wm * 2 + mr) * 2 + kc) * 512 + lane * 8]);
#pragma unroll
            for (int nr = 0; nr < 2; nr++)
                bfr[nr] = ld_frag(&FB[(8 + (wn * 2 + nr) * 2 + kc) * 512 + lane * 8]);
#pragma unroll
            for (int mr = 0; mr < 2; mr++)
#pragma unroll
                for (int nr = 0; nr < 2; nr++)
                    acc[mr][nr] = mfma_b(af[mr], bfr[nr], acc[mr][nr]);
        }
        __syncthreads();
    }

#pragma unroll
    for (int mr = 0; mr < 2; mr++)
#pragma unroll
        for (int nr = 0; nr < 2; nr++)
#pragma unroll
            for (int r = 0; r < 16; r++) {
                int row = mt * 128 + wm * 64 + mr * 32 + (r & 3) + 8 * (r >> 2) + 4 * h;
                int col = nt * 128 + wn * 64 + nr * 32 + l31;
                if (col < DIMF) {
                    float v = acc[mr][nr][r] + bias[col] + tres[row * DIMF + col];
                    feat[row * FDIM + mod * DIMF + col] = v;
                }
            }
}

// ---------------------------------------------------------------- LN + head
__global__ __launch_bounds__(256, 1) void ln_head(
    const float* __restrict__ feat, const float* __restrict__ gam,
    const float* __restrict__ bet, const float* __restrict__ Wh,
    const float* __restrict__ bh, float* __restrict__ out)
{
    const int row = blockIdx.x;
    const float* x = feat + row * FDIM;
    const int tid = threadIdx.x;
    float v[7];
    float s = 0.f, ss = 0.f;
#pragma unroll
    for (int i = 0; i < 7; i++) {
        int idx = tid + i * 256;
        float val = (idx < FDIM) ? x[idx] : 0.f;
        v[i] = val; s += val; ss += val * val;
    }
#pragma unroll
    for (int m = 1; m < 64; m <<= 1) { s += __shfl_xor(s, m, 64); ss += __shfl_xor(ss, m, 64); }
    __shared__ float red[8];
    const int w = tid >> 6, lane = tid & 63;
    if (lane == 0) { red[w] = s; red[4 + w] = ss; }
    __syncthreads();
    s = red[0] + red[1] + red[2] + red[3];
    ss = red[4] + red[5] + red[6] + red[7];
    const float mu = s / (float)FDIM;
    const float var = ss / (float)FDIM - mu * mu;
    const float rstd = rsqrtf(var + 1e-5f);
    float a0 = 0.f, a1 = 0.f;
#pragma unroll
    for (int i = 0; i < 7; i++) {
        int idx = tid + i * 256;
        if (idx < FDIM) {
            float nv = (v[i] - mu) * rstd * gam[idx] + bet[idx];
            a0 += nv * Wh[idx * 2];
            a1 += nv * Wh[idx * 2 + 1];
        }
    }
#pragma unroll
    for (int m = 1; m < 64; m <<= 1) { a0 += __shfl_xor(a0, m, 64); a1 += __shfl_xor(a1, m, 64); }
    __shared__ float red2[8];
    if (lane == 0) { red2[w] = a0; red2[4 + w] = a1; }
    __syncthreads();
    if (tid == 0) {
        out[row * 2 + 0] = red2[0] + red2[1] + red2[2] + red2[3] + bh[0];
        out[row * 2 + 1] = red2[4] + red2[5] + red2[6] + red2[7] + bh[1];
    }
}

// ---------------------------------------------------------------- launch
extern "C" void kernel_launch(void* const* d_in, const int* in_sizes, int n_in,
                              void* d_out, int out_size, void* d_ws, size_t ws_size,
                              hipStream_t stream)
{
    const float* t1    = (const float*)d_in[0];
    const float* t2    = (const float*)d_in[1];
    const float* t1c   = (const float*)d_in[2];
    const float* Wqkv1 = (const float*)d_in[3];
    const float* bqkv1 = (const float*)d_in[4];
    const float* Wqkv2 = (const float*)d_in[5];
    const float* bqkv2 = (const float*)d_in[6];
    const float* Wqkv3 = (const float*)d_in[7];
    const float* bqkv3 = (const float*)d_in[8];
    const float* Wo1   = (const float*)d_in[9];
    const float* bo1   = (const float*)d_in[10];
    const float* Wo2   = (const float*)d_in[11];
    const float* bo2   = (const float*)d_in[12];
    const float* Wo3   = (const float*)d_in[13];
    const float* bo3   = (const float*)d_in[14];
    const float* ln_g  = (const float*)d_in[15];
    const float* ln_b  = (const float*)d_in[16];
    const float* Wh    = (const float*)d_in[17];
    const float* bh    = (const float*)d_in[18];

    char* ws = (char*)d_ws;
    size_t off = 0;
    u16* tA    = (u16*)(ws + off); off += (size_t)3 * N_TOK * KPAD * 2;
    u16* WqkvT = (u16*)(ws + off); off += (size_t)3 * OUT3 * KPAD * 2;
    u16* WoT   = (u16*)(ws + off); off += (size_t)3 * DIMP * RDIM * 2;
    u16* qbuf  = (u16*)(ws + off); off += (size_t)3 * N_TOK * OUTD * 2;
    u16* kbuf  = (u16*)(ws + off); off += (size_t)3 * N_TOK * OUTD * 2;
    u16* vT    = (u16*)(ws + off); off += (size_t)3 * OUTD * N_TOK * 2;
    u16* rbuf  = (u16*)(ws + off); off += (size_t)3 * N_TOK * RDIM * 2;
    u16* Opart = (u16*)(ws + off); off += (size_t)NCHUNK * 6 * N_TOK * OUTD * 2;
    float* lpart = (float*)(ws + off); off += (size_t)NCHUNK * 6 * N_TOK * 4;

    float* out  = (float*)d_out;
    float* feat = out + N_TOK * 2;

    const int ta_total = 3 * N_TOK * (KPAD / 2);
    prep_ta<<<(ta_total + 255) / 256, 256, 0, stream>>>(t1, t2, t1c, tA);
    prep_wq<<<dim3(OUT3 / 32, KPAD / 32, 3), 256, 0, stream>>>(
        Wqkv1, Wqkv2, Wqkv3, WqkvT);
    prep_wo<<<dim3(DIMP / 32, RDIM / 32, 3), 256, 0, stream>>>(
        Wo1, Wo2, Wo3, WoT);

    qkv_gemm<<<dim3(32, 6, 3), 256, 0, stream>>>(
        tA, WqkvT, bqkv1, bqkv2, bqkv3, qbuf, kbuf, vT);

    attn_kernel<<<dim3(32, 6, NCHUNK), 256, 0, stream>>>(qbuf, kbuf, vT, Opart, lpart);

    combine_kernel<<<dim3(N_TOK / 4, 6), 256, 0, stream>>>(Opart, lpart, kbuf, rbuf);

    proj_gemm<<<dim3(32, 5, 3), 256, 0, stream>>>(
        rbuf, WoT, bo1, bo2, bo3, t1, t2, t1c, feat);

    ln_head<<<4096, 256, 0, stream>>>(feat, ln_g, ln_b, Wh, bh, out);
}